// Round 10
// baseline (159.735 us; speedup 1.0000x reference)
//
#include <hip/hip_runtime.h>

#define NROW 8192
#define DIM  256
#define INV_T 5.0f

typedef _Float16 f16x8 __attribute__((ext_vector_type(8)));
typedef _Float16 f16x4 __attribute__((ext_vector_type(4)));
typedef float    f32x4 __attribute__((ext_vector_type(4)));
typedef unsigned long long u64;

__device__ __forceinline__ void gload_lds16(const void* g, void* l) {
  __builtin_amdgcn_global_load_lds(
      (__attribute__((address_space(1))) void*)(g),
      (__attribute__((address_space(3))) void*)(l),
      16, 0, 0);
}

// ---------------- normalize rows + convert to fp16 ----------------
__global__ __launch_bounds__(256) void norm_kernel(
    const float* __restrict__ zv, const float* __restrict__ zf,
    _Float16* __restrict__ ov, _Float16* __restrict__ of) {
  const float* in  = blockIdx.y ? zf : zv;
  _Float16*    out = blockIdx.y ? of : ov;
  int row  = blockIdx.x * 4 + (threadIdx.x >> 6);
  int lane = threadIdx.x & 63;
  float4 v = ((const float4*)(in + (size_t)row * DIM))[lane];
  float ss = v.x * v.x + v.y * v.y + v.z * v.z + v.w * v.w;
#pragma unroll
  for (int off = 1; off < 64; off <<= 1) ss += __shfl_xor(ss, off);
  float inv = 1.0f / fmaxf(sqrtf(ss), 1e-12f);
  f16x4 o;
  o.x = (_Float16)(v.x * inv);
  o.y = (_Float16)(v.y * inv);
  o.z = (_Float16)(v.z * inv);
  o.w = (_Float16)(v.w * inv);
  ((f16x4*)(out + (size_t)row * DIM))[lane] = o;
}

// ---------------- main kernel: G-blocks (dense GEMM+exp) + S-blocks (Gf->bitmask) ----
// 3072 blocks, 48 KB LDS each -> 3 blocks/CU. bid%3==0: G (1024), else S (2048).
// S stages Gf via global_load_lds (4 KB/wave in flight) -> HBM saturation;
// G is the mask-free dense-E GEMM whose stalls S-waves cover.
__global__ __launch_bounds__(256, 3) void main_kernel(
    const _Float16* __restrict__ zv, const _Float16* __restrict__ zf,
    const float* __restrict__ Gf,
    float* __restrict__ Ep, u64* __restrict__ Mask) {

  __shared__ __align__(16) char lds[49152];   // 48 KB

  const int bid  = blockIdx.x;
  const int t_   = threadIdx.x;
  const int lane = t_ & 63;
  const int w    = t_ >> 6;

  if (bid % 3 == 0) {
    // =================== G-block: dense E_i partials, 64x1024 region ===================
    _Float16* Asf = (_Float16*)lds;              // 64 x 256 fp16 = 32 KB
    _Float16* Bs  = (_Float16*)(lds + 32768);    // 2 x (128 x 32) fp16 = 16 KB
    const int g    = bid / 3;
    const int cb   = bid & 7;                    // XCD-affine column slice
    const int rb   = g >> 3;                     // 0..127
    const int row0 = rb * 64;
    const int col0 = cb * 1024;
    const int wr   = w >> 1;
    const int wc   = w & 1;
    const int l15  = lane & 15;
    const int kq   = lane >> 4;

    // stage A tile (64 x 256), source pre-swizzled
#pragma unroll
    for (int c = 0; c < 8; ++c) {
      int i = c * 256 + t_;
      int rowi = i >> 5, cbP = i & 31;
      int cbL = cbP ^ (rowi & 7);
      gload_lds16(zv + (size_t)(row0 + rowi) * DIM + cbL * 8,
                  &Asf[(size_t)(c * 256 + w * 64) * 8]);
    }

    auto stageB = [&](int buf, int s) {
      int tt = s >> 3, kk = s & 7;
      int ct0 = col0 + tt * 128;
      int k0 = kk * 32;
#pragma unroll
      for (int c2 = 0; c2 < 2; ++c2) {
        int i = c2 * 256 + t_;
        int rowi = i >> 2, cbP = i & 3;
        int cbL = cbP ^ ((rowi >> 1) & 3);
        gload_lds16(zf + (size_t)(ct0 + rowi) * DIM + k0 + cbL * 8,
                    &Bs[(size_t)buf * 4096 + (size_t)(c2 * 256 + w * 64) * 8]);
      }
    };

    stageB(0, 0);
    asm volatile("s_waitcnt vmcnt(0)" ::: "memory");
    __syncthreads();

    f32x4 acc[2][4];
    float Sa[8];
#pragma unroll
    for (int i = 0; i < 8; ++i) Sa[i] = 0.0f;

#pragma unroll 2
    for (int s = 0; s < 64; ++s) {
      const int cur = s & 1;
      if ((s & 7) == 0) {
#pragma unroll
        for (int m = 0; m < 2; ++m)
#pragma unroll
          for (int n = 0; n < 4; ++n) acc[m][n] = (f32x4)(0.0f);
      }
      if (s < 63) stageB(cur ^ 1, s + 1);

      const int k0c = (s & 7) * 4;
      f16x8 af[2], bf[4];
#pragma unroll
      for (int m = 0; m < 2; ++m) {
        int rowA = wr * 32 + m * 16 + l15;
        int cbP = (k0c + kq) ^ (rowA & 7);
        af[m] = *(const f16x8*)&Asf[(size_t)rowA * 256 + cbP * 8];
      }
#pragma unroll
      for (int n = 0; n < 4; ++n) {
        int rowB = wc * 64 + n * 16 + l15;
        int cbP = kq ^ ((rowB >> 1) & 3);
        bf[n] = *(const f16x8*)&Bs[(size_t)cur * 4096 + (size_t)rowB * 32 + cbP * 8];
      }
#pragma unroll
      for (int m = 0; m < 2; ++m)
#pragma unroll
        for (int n = 0; n < 4; ++n)
          acc[m][n] = __builtin_amdgcn_mfma_f32_16x16x32_f16(af[m], bf[n], acc[m][n], 0, 0, 0);

      if ((s & 7) == 7) {
#pragma unroll
        for (int m = 0; m < 2; ++m)
#pragma unroll
          for (int n = 0; n < 4; ++n)
#pragma unroll
            for (int r = 0; r < 4; ++r)
              Sa[m * 4 + r] += __expf(acc[m][n][r] * INV_T);
      }
      asm volatile("s_waitcnt vmcnt(0)" ::: "memory");
      __syncthreads();
    }

#pragma unroll
    for (int off = 1; off <= 8; off <<= 1)
#pragma unroll
      for (int i = 0; i < 8; ++i) Sa[i] += __shfl_xor(Sa[i], off);

    const int slot = cb * 2 + wc;   // 16 slots
#pragma unroll
    for (int i = 0; i < 8; ++i) {
      if (l15 == i) {
        int m = i >> 2, r = i & 3;
        int row = row0 + wr * 32 + m * 16 + kq * 4 + r;
        Ep[(size_t)slot * NROW + row] = Sa[i];
      }
    }
  } else {
    // =================== S-block: Gf -> bitmask via deep gload_lds pipeline ============
    // wave w owns one full row; 8 chunks of 1024 cols; LDS 2 x 4 KB per wave.
    const int q    = bid / 3;
    const int sidx = q * 2 + (bid % 3) - 1;      // 0..2047
    const int row  = sidx * 4 + w;
    const float* gsrc = Gf + (size_t)row * NROW;
    char* wreg = lds + w * 8192;                  // this wave's 8 KB
    u64* mrow = Mask + (size_t)row * 128;

    auto stageS = [&](int buf, int c) {
      const float* src = gsrc + c * 1024;
      char* dst = wreg + buf * 4096;
#pragma unroll
      for (int i = 0; i < 4; ++i)
        gload_lds16(src + i * 256 + lane * 4, dst + i * 1024);
    };

    stageS(0, 0);
#pragma unroll 1
    for (int c = 0; c < 8; ++c) {
      if (c < 7) {
        stageS((c + 1) & 1, c + 1);
        asm volatile("s_waitcnt vmcnt(4)" ::: "memory");
      } else {
        asm volatile("s_waitcnt vmcnt(0)" ::: "memory");
      }
      const char* src = wreg + (c & 1) * 4096;
      u64 bb[4][4];
#pragma unroll
      for (int i = 0; i < 4; ++i) {
        float4 qv = *(const float4*)(src + i * 1024 + lane * 16);
        bb[i][0] = __ballot(qv.x > 0.0f);
        bb[i][1] = __ballot(qv.y > 0.0f);
        bb[i][2] = __ballot(qv.z > 0.0f);
        bb[i][3] = __ballot(qv.w > 0.0f);
      }
      u64* mw = mrow + c * 16;
#pragma unroll
      for (int i = 0; i < 4; ++i)
#pragma unroll
        for (int j = 0; j < 4; ++j)
          if (lane == i * 4 + j) mw[i * 4 + j] = bb[i][j];
    }
  }
}

// ---------------- sparse pass: bitmask -> per-row P, E_pos, C (deterministic) -------
__global__ __launch_bounds__(256) void sparse_kernel(
    const _Float16* __restrict__ zv, const _Float16* __restrict__ zf,
    const u64* __restrict__ Mask,
    float* __restrict__ Pr, float* __restrict__ Er, float* __restrict__ Cr) {
  const int i    = blockIdx.x * 4 + (threadIdx.x >> 6);
  const int lane = threadIdx.x & 63;
  f16x4 a16 = *(const f16x4*)(zv + (size_t)i * DIM + lane * 4);
  const float a0 = (float)a16[0], a1 = (float)a16[1];
  const float a2 = (float)a16[2], a3 = (float)a16[3];
  const u64* mb = Mask + (size_t)i * 128;
  u64 m0 = mb[lane];
  u64 m1 = mb[64 + lane];
  float P = 0.0f, E = 0.0f, C = 0.0f;
  bool dseen = false;
#pragma unroll 1
  for (int g = 0; g < 128; ++g) {
    u64 wd = __shfl((g < 64) ? m0 : m1, g & 63);
    while (wd) {
      int b = (int)__builtin_ctzll(wd);
      wd &= wd - 1;
      int j = (g >> 2) * 256 + b * 4 + (g & 3);
      f16x4 b16 = *(const f16x4*)(zf + (size_t)j * DIM + lane * 4);
      float d = a0 * (float)b16[0] + a1 * (float)b16[1] +
                a2 * (float)b16[2] + a3 * (float)b16[3];
#pragma unroll
      for (int off = 1; off < 64; off <<= 1) d += __shfl_xor(d, off);
      float sim = d * INV_T;
      P += sim;
      E += __expf(sim);
      C += 1.0f;
      dseen = dseen || (j == i);
    }
  }
  if (!dseen) {   // diagonal not in Gf: append (fixed order -> deterministic)
    f16x4 b16 = *(const f16x4*)(zf + (size_t)i * DIM + lane * 4);
    float d = a0 * (float)b16[0] + a1 * (float)b16[1] +
              a2 * (float)b16[2] + a3 * (float)b16[3];
#pragma unroll
    for (int off = 1; off < 64; off <<= 1) d += __shfl_xor(d, off);
    float sim = d * INV_T;
    P += sim;
    E += __expf(sim);
    C += 1.0f;
  }
  if (lane == 0) { Pr[i] = P; Er[i] = E; Cr[i] = C; }
}

// ---------------- per-row loss + block partials (deterministic) ----------------
__global__ __launch_bounds__(256) void loss_partial_kernel(
    const float* __restrict__ Ep, const float* __restrict__ Pr,
    const float* __restrict__ Er, const float* __restrict__ Cr,
    float* __restrict__ bsum) {
  int row = blockIdx.x * 256 + threadIdx.x;
  float E = 0.0f;
#pragma unroll
  for (int s2 = 0; s2 < 16; ++s2) E += Ep[(size_t)s2 * NROW + row];
  float P = Pr[row], sE = Er[row], C = Cr[row];
  float S = E - sE + C;                 // neg exps + exp(0) per pos slot
  float pos = P / (C + 1e-8f);
  float contrib = __logf(S + __expf(pos)) - pos;
#pragma unroll
  for (int off = 1; off < 64; off <<= 1) contrib += __shfl_xor(contrib, off);
  __shared__ float wsum[4];
  if ((threadIdx.x & 63) == 0) wsum[threadIdx.x >> 6] = contrib;
  __syncthreads();
  if (threadIdx.x == 0) bsum[blockIdx.x] = wsum[0] + wsum[1] + wsum[2] + wsum[3];
}

__global__ void loss_final_kernel(const float* __restrict__ bsum, float* __restrict__ out) {
  int lane = threadIdx.x;
  float v = (lane < 32) ? bsum[lane] : 0.0f;
#pragma unroll
  for (int off = 1; off < 64; off <<= 1) v += __shfl_xor(v, off);
  if (lane == 0) out[0] = v / (float)NROW;
}

extern "C" void kernel_launch(void* const* d_in, const int* in_sizes, int n_in,
                              void* d_out, int out_size, void* d_ws, size_t ws_size,
                              hipStream_t stream) {
  const float* zv = (const float*)d_in[0];
  const float* zf = (const float*)d_in[1];
  const float* Gf = (const float*)d_in[2];
  float* out = (float*)d_out;

  char* ws = (char*)d_ws;
  _Float16* zv16 = (_Float16*)ws;                                   // 4 MB
  _Float16* zf16 = zv16 + (size_t)NROW * DIM;                       // 4 MB
  float* Ep = (float*)(ws + (8u << 20));                            // 512 KB
  float* Pr = (float*)(ws + (9u << 20));
  float* Er = Pr + NROW;
  float* Cr = Er + NROW;
  float* bsum = Cr + NROW;                                          // 32 floats
  u64* Mask = (u64*)(ws + (16u << 20));                             // 8 MB

  norm_kernel<<<dim3(NROW / 4, 2), 256, 0, stream>>>(zv, zf, zv16, zf16);
  main_kernel<<<3072, 256, 0, stream>>>(zv16, zf16, Gf, Ep, Mask);
  sparse_kernel<<<NROW / 4, 256, 0, stream>>>(zv16, zf16, Mask, Pr, Er, Cr);
  loss_partial_kernel<<<NROW / 256, 256, 0, stream>>>(Ep, Pr, Er, Cr, bsum);
  loss_final_kernel<<<1, 64, 0, stream>>>(bsum, out);
}